// Round 1
// baseline (514.948 us; speedup 1.0000x reference)
//
#include <hip/hip_runtime.h>
#include <math.h>

#define BATCH 2048
#define N_TIME 2048
#define INPUT_SIZE 28
#define OUTPUT_SIZE 7
#define N_S 4
#define PERIOD 7
#define EMBED 9
#define SEAS_LEN (N_TIME + PERIOD)      // 2055
#define W_COUNT 288                      // len(range(0, 2014, 7))
#define WB_COUNT (W_COUNT * BATCH)       // 589824
#define INS_COLS 67                      // 28 + 35 + 4
#define TOT_COLS 74                      // 67 + 7
#define OUT0_SIZE (WB_COUNT * INS_COLS)  // 39,518,208
#define OUT1_SIZE (WB_COUNT * OUTPUT_SIZE) // 4,128,768
#define LEV_SIZE (BATCH * N_TIME)        // 4,194,304
#define SEAS_SIZE (BATCH * SEAS_LEN)     // 4,208,640

// ---------------------------------------------------------------------------
// Phase 1: per-row exponential smoothing scan. One thread per batch row.
// Strictly sequential in t; critical path is one fma per step on `lev`
// (rcp(s) uses state from 7 steps earlier, rcp(newlev) feeds state 7 steps
// later -> both off the critical chain). Unroll-by-7 keeps buf[] in regs.
// ---------------------------------------------------------------------------
__global__ __launch_bounds__(64) void es_scan(
    const float* __restrict__ Y, const int* __restrict__ idxs,
    const float* __restrict__ emb,
    float* __restrict__ levels, float* __restrict__ seasonal)
{
    int b = blockIdx.x * 64 + threadIdx.x;
    if (b >= BATCH) return;
    const float* Yb   = Y + (size_t)b * N_TIME;
    float* levb       = levels + (size_t)b * N_TIME;
    float* seab       = seasonal + (size_t)b * SEAS_LEN;

    const float* e = emb + (size_t)idxs[b] * EMBED;
    float lev_sms  = 1.0f / (1.0f + expf(-e[0]));
    float seas_sms = 1.0f / (1.0f + expf(-e[1]));
    float is[PERIOD];
#pragma unroll
    for (int j = 0; j < PERIOD; ++j) is[j] = expf(e[2 + j]);

    float lev = Yb[0] / is[0];
    levb[0] = lev;
#pragma unroll
    for (int j = 0; j < PERIOD; ++j) seab[j] = is[j];
    seab[PERIOD] = is[0];

    // buf0 = rotate-left(init_seas): buf[j] = is[(j+1)%7]
    float buf[PERIOD];
#pragma unroll
    for (int j = 0; j < PERIOD; ++j) buf[j] = is[(j + 1) % PERIOD];

    const float oma = 1.0f - lev_sms;
    const float oms = 1.0f - seas_sms;

    int kk = 0;
    // 2047 steps = 292*7 + 3.  step index kk+u, (kk+u)%7 == u since kk%7==0.
#pragma unroll 1
    for (int outer = 0; outer < 292; ++outer) {
        float yv[PERIOD];
#pragma unroll
        for (int u = 0; u < PERIOD; ++u) yv[u] = Yb[kk + 1 + u];
#pragma unroll
        for (int u = 0; u < PERIOD; ++u) {
            float y  = yv[u];
            float s  = buf[u];
            float nl = fmaf(lev_sms, y * __builtin_amdgcn_rcpf(s), oma * lev);
            float ns = fmaf(seas_sms, y * __builtin_amdgcn_rcpf(nl), oms * s);
            buf[u] = ns;
            lev = nl;
            levb[kk + 1 + u] = nl;
            seab[kk + 8 + u] = ns;
        }
        kk += 7;
    }
    // remainder: kk = 2044, steps u = 0,1,2
#pragma unroll
    for (int u = 0; u < 3; ++u) {
        float y  = Yb[kk + 1 + u];
        float s  = buf[u];
        float nl = fmaf(lev_sms, y * __builtin_amdgcn_rcpf(s), oma * lev);
        float ns = fmaf(seas_sms, y * __builtin_amdgcn_rcpf(nl), oms * s);
        buf[u] = ns;
        lev = nl;
        levb[kk + 1 + u] = nl;
        seab[kk + 8 + u] = ns;
    }
}

// ---------------------------------------------------------------------------
// Phase 2: window materialization. One thread per element of the fused
// (W,B,67) insample + (W,B,7) outsample layout, j fastest -> coalesced writes.
// ---------------------------------------------------------------------------
__global__ __launch_bounds__(256) void es_windows(
    const float* __restrict__ Y, const float* __restrict__ X,
    const float* __restrict__ S, const float* __restrict__ levels,
    const float* __restrict__ seasonal,
    float* __restrict__ out0, float* __restrict__ out1)
{
    int idx = blockIdx.x * 256 + threadIdx.x;
    if (idx >= WB_COUNT * TOT_COLS) return;
    int wb = idx / TOT_COLS;          // 0 .. 589823
    int j  = idx - wb * TOT_COLS;     // 0 .. 73
    int w  = wb >> 11;                // / 2048
    int b  = wb & (BATCH - 1);
    int t0 = w * 7;

    if (j < INPUT_SIZE) {
        int t    = t0 + j;
        float y  = Y[b * N_TIME + t];
        float lv = levels[b * N_TIME + t0 + INPUT_SIZE - 1];
        float sv = seasonal[b * SEAS_LEN + t];
        out0[wb * INS_COLS + j] = logf(y / (lv * sv));
    } else if (j < INPUT_SIZE + 35) {              // N_T*(IN+OUT) = 35
        out0[wb * INS_COLS + j] = X[b * N_TIME + t0 + (j - INPUT_SIZE)];
    } else if (j < INS_COLS) {
        out0[wb * INS_COLS + j] = S[b * N_S + (j - 63)];
    } else {
        int jo = j - INS_COLS;
        out1[wb * OUTPUT_SIZE + jo] = Y[b * N_TIME + t0 + INPUT_SIZE + jo];
    }
}

extern "C" void kernel_launch(void* const* d_in, const int* in_sizes, int n_in,
                              void* d_out, int out_size, void* d_ws, size_t ws_size,
                              hipStream_t stream) {
    const float* S    = (const float*)d_in[0];
    const float* Y    = (const float*)d_in[1];
    const float* X    = (const float*)d_in[2];
    const int*   idxs = (const int*)d_in[3];
    const float* emb  = (const float*)d_in[4];
    // d_in[5] = step_size (always 7; window count baked into W_COUNT)

    float* out      = (float*)d_out;
    float* out_ins  = out;                               // (W,B,67)
    float* out_outs = out + OUT0_SIZE;                   // (W,B,7)
    float* levels   = out + OUT0_SIZE + OUT1_SIZE;       // (B,2048)
    float* seasonal = out + OUT0_SIZE + OUT1_SIZE + LEV_SIZE; // (B,2055)

    es_scan<<<BATCH / 64, 64, 0, stream>>>(Y, idxs, emb, levels, seasonal);

    const int total = WB_COUNT * TOT_COLS;               // 43,646,976
    es_windows<<<(total + 255) / 256, 256, 0, stream>>>(
        Y, X, S, levels, seasonal, out_ins, out_outs);
}